// Round 2
// baseline (7253.013 us; speedup 1.0000x reference)
//
#include <hip/hip_runtime.h>
#include <hip/hip_bf16.h>

#define NPIX 16384          // 128*128
#define S_TOT 262144        // 128*128*16

__device__ __forceinline__ float lrelu(float v) { return v > 0.f ? v : 0.2f * v; }

// ---- device-global scratch (write-before-read each call; no d_ws dependency) ----
__device__ float g_alpha[5 * 256];
__device__ float g_beta[5 * 256];
__device__ float g_amod[1024];          // zc = z@wz^T+bz ; a0|a1|a2|a3
__device__ float g_sigma[S_TOT];
__device__ float g_c[S_TOT * 64];
__device__ float g_feat[64 * NPIX];
__device__ float g_bufA[256 * NPIX];
__device__ float g_bufB[256 * NPIX];
__device__ float g_bufC[256 * NPIX];

// ---------------- kparams: z-dependent constants (1 block) ----------------
__global__ __launch_bounds__(256) void kparams(const float* __restrict__ z,
    const float* __restrict__ wa, const float* __restrict__ ba,
    const float* __restrict__ wb, const float* __restrict__ bb,
    const float* __restrict__ wz, const float* __restrict__ bz) {
  __shared__ float zs[256];
  const int t = threadIdx.x;
  zs[t] = z[t];
  __syncthreads();
  for (int l = 0; l < 5; ++l) {
    float accA = ba[l * 256 + t];
    float accB = bb[l * 256 + t];
    const float* rowA = wa + (l * 256 + t) * 256;
    const float* rowB = wb + (l * 256 + t) * 256;
    for (int k = 0; k < 256; k += 4) {
      float4 va = *(const float4*)(rowA + k);
      float4 vb = *(const float4*)(rowB + k);
      accA += va.x * zs[k] + va.y * zs[k + 1] + va.z * zs[k + 2] + va.w * zs[k + 3];
      accB += vb.x * zs[k] + vb.y * zs[k + 1] + vb.z * zs[k + 2] + vb.w * zs[k + 3];
    }
    g_alpha[l * 256 + t] = accA;
    g_beta[l * 256 + t] = accB;
  }
  for (int j = t; j < 1024; j += 256) {
    float acc = bz[j];
    const float* row = wz + j * 256;
    for (int k = 0; k < 256; k += 4) {
      float4 v = *(const float4*)(row + k);
      acc += v.x * zs[k] + v.y * zs[k + 1] + v.z * zs[k + 2] + v.w * zs[k + 3];
    }
    g_amod[j] = acc;
  }
}

// ---------------- fused MLP: 64 samples / block ----------------
// microtile: thread (sg=tid>>5, og=tid&31) computes samples sg*8..+7 x channels og+j*32
__device__ __forceinline__ void gemm8x8(const float* __restrict__ fin, int K,
    const float* __restrict__ W, const float* __restrict__ alpha,
    float* __restrict__ wst, float acc[8][8], int tid, int sg, int og) {
#pragma unroll 1
  for (int kc = 0; kc < K; kc += 8) {
    {  // stage 8 k-slices of W (x alpha) transposed into wst[k'][o]
      float4 v0 = *(const float4*)(W + tid * K + kc);
      float4 v1 = *(const float4*)(W + tid * K + kc + 4);
      float wv8[8] = {v0.x, v0.y, v0.z, v0.w, v1.x, v1.y, v1.z, v1.w};
      if (alpha) {
#pragma unroll
        for (int e = 0; e < 8; ++e) wst[e * 256 + tid] = wv8[e] * alpha[kc + e];
      } else {
#pragma unroll
        for (int e = 0; e < 8; ++e) wst[e * 256 + tid] = wv8[e];
      }
    }
    __syncthreads();
    float fqf[8][8];
#pragma unroll
    for (int i = 0; i < 8; ++i) {
      const float* fr = fin + (sg * 8 + i) * K + kc;
      float4 a = *(const float4*)fr;
      float4 b4 = *(const float4*)(fr + 4);
      fqf[i][0] = a.x; fqf[i][1] = a.y; fqf[i][2] = a.z; fqf[i][3] = a.w;
      fqf[i][4] = b4.x; fqf[i][5] = b4.y; fqf[i][6] = b4.z; fqf[i][7] = b4.w;
    }
#pragma unroll
    for (int kk = 0; kk < 8; ++kk) {
      float wv[8];
#pragma unroll
      for (int j = 0; j < 8; ++j) wv[j] = wst[kk * 256 + og + j * 32];
#pragma unroll
      for (int i = 0; i < 8; ++i) {
#pragma unroll
        for (int j = 0; j < 8; ++j) acc[i][j] += fqf[i][kk] * wv[j];
      }
    }
    __syncthreads();
  }
}

__global__ __launch_bounds__(256) void kmlp(
    const float* __restrict__ x, const float* __restrict__ m_in,
    const float* __restrict__ w1, const float* __restrict__ b1, const float* __restrict__ wma,
    const float* __restrict__ mlw,
    const float* __restrict__ wsig, const float* __restrict__ bsig,
    const float* __restrict__ wc, const float* __restrict__ bc) {
  __shared__ float fA[64 * 256];
  __shared__ float fB[64 * 256];
  __shared__ float wst[8 * 256];
  __shared__ float mbuf[64 * 8];
  const int tid = threadIdx.x;
  const int s0 = blockIdx.x * 64;
  const int sg = tid >> 5, og = tid & 31;

  {  // stage x tile [64][128] -> fA (flat), m tile -> mbuf[64][8]
    const float* xp = x + (size_t)s0 * 128;
#pragma unroll
    for (int q = 0; q < 8; ++q) {
      int i4 = tid + q * 256;
      *(float4*)&fA[i4 * 4] = *(const float4*)&xp[i4 * 4];
    }
    if (tid < 112) {
      const float* mp = m_in + (size_t)s0 * 7;
      float4 v = *(const float4*)(mp + tid * 4);
      float vv[4] = {v.x, v.y, v.z, v.w};
#pragma unroll
      for (int e = 0; e < 4; ++e) {
        int idx = tid * 4 + e;
        int ss = idx / 7, qq = idx - ss * 7;
        mbuf[ss * 8 + qq] = vv[e];
      }
    }
  }
  __syncthreads();

  float acc[8][8];
#pragma unroll
  for (int i = 0; i < 8; ++i)
#pragma unroll
    for (int j = 0; j < 8; ++j) acc[i][j] = 0.f;

  // L1: f = lrelu(x@w1^T + b1 + m@wma^T)   -> fB
  gemm8x8(fA, 128, w1, nullptr, wst, acc, tid, sg, og);
#pragma unroll
  for (int j = 0; j < 8; ++j) {
    const int o = og + j * 32;
    float w7[7];
#pragma unroll
    for (int q = 0; q < 7; ++q) w7[q] = wma[o * 7 + q];
    const float b1v = b1[o];
#pragma unroll
    for (int i = 0; i < 8; ++i) {
      const int ss = sg * 8 + i;
      float v = acc[i][j] + b1v;
#pragma unroll
      for (int q = 0; q < 7; ++q) v += mbuf[ss * 8 + q] * w7[q];
      fB[ss * 256 + o] = lrelu(v);
    }
  }

  // 5 ModLinear layers (alpha folded into W at stage time, beta in epilogue)
  for (int l = 0; l < 5; ++l) {
    float* fin = (l & 1) ? fA : fB;
    float* fout = (l & 1) ? fB : fA;
#pragma unroll
    for (int i = 0; i < 8; ++i)
#pragma unroll
      for (int j = 0; j < 8; ++j) acc[i][j] = 0.f;
    gemm8x8(fin, 256, mlw + l * 65536, g_alpha + l * 256, wst, acc, tid, sg, og);
#pragma unroll
    for (int j = 0; j < 8; ++j) {
      const int o = og + j * 32;
      const float be = g_beta[l * 256 + o];
#pragma unroll
      for (int i = 0; i < 8; ++i) {
        const int ss = sg * 8 + i;
        fout[ss * 256 + o] = lrelu(acc[i][j] + be);
      }
    }
    if (l == 2) {  // sigma tap after fc_4
      __syncthreads();
      if (tid < 64) {
        float a = bsig[0];
        const float* fr = fout + tid * 256;
        for (int k = 0; k < 256; ++k) a += fr[k] * wsig[k];
        g_sigma[s0 + tid] = a;
      }
    }
  }

  // c = f@wc^T + bc  (final f is in fA), write fp32 to g_c
  {
    float acc2[4][4];
#pragma unroll
    for (int i = 0; i < 4; ++i)
#pragma unroll
      for (int j = 0; j < 4; ++j) acc2[i][j] = 0.f;
    const int sg2 = tid >> 4, og2 = tid & 15;
#pragma unroll 1
    for (int kc = 0; kc < 256; kc += 8) {
      if (tid < 64) {
        float4 v0 = *(const float4*)(wc + tid * 256 + kc);
        float4 v1 = *(const float4*)(wc + tid * 256 + kc + 4);
        float wv8[8] = {v0.x, v0.y, v0.z, v0.w, v1.x, v1.y, v1.z, v1.w};
#pragma unroll
        for (int e = 0; e < 8; ++e) wst[e * 64 + tid] = wv8[e];
      }
      __syncthreads();
      float fq2[4][8];
#pragma unroll
      for (int i = 0; i < 4; ++i) {
        const float* fr = fA + (sg2 * 4 + i) * 256 + kc;
        float4 a = *(const float4*)fr;
        float4 b4 = *(const float4*)(fr + 4);
        fq2[i][0] = a.x; fq2[i][1] = a.y; fq2[i][2] = a.z; fq2[i][3] = a.w;
        fq2[i][4] = b4.x; fq2[i][5] = b4.y; fq2[i][6] = b4.z; fq2[i][7] = b4.w;
      }
#pragma unroll
      for (int kk = 0; kk < 8; ++kk) {
        float wv[4];
#pragma unroll
        for (int j = 0; j < 4; ++j) wv[j] = wst[kk * 64 + og2 + j * 16];
#pragma unroll
        for (int i = 0; i < 4; ++i)
#pragma unroll
          for (int j = 0; j < 4; ++j) acc2[i][j] += fq2[i][kk] * wv[j];
      }
      __syncthreads();
    }
#pragma unroll
    for (int j = 0; j < 4; ++j) {
      const int o = og2 + j * 16;
      const float bcv = bc[o];
#pragma unroll
      for (int i = 0; i < 4; ++i) {
        const int ss = sg2 * 4 + i;
        g_c[(size_t)(s0 + ss) * 64 + o] = acc2[i][j] + bcv;
      }
    }
  }
}

// ---------------- volumetric compositing: 4 pixels / block ----------------
__global__ __launch_bounds__(256) void kcomposite(const float* __restrict__ dists) {
  const int tid = threadIdx.x;
  const int p = blockIdx.x * 4 + (tid >> 6);
  const int ch = tid & 63;
  const int base = p * 16;
  float T = 1.f, acc = 0.f;
  for (int mm = 0; mm < 16; ++mm) {
    float sgm = g_sigma[base + mm];
    float d = dists[base + mm];
    float a = 1.f - expf(-fmaxf(sgm, 0.f) * d);
    acc += a * T * g_c[(size_t)(base + mm) * 64 + ch];
    T *= (1.f - a + 1e-10f);
  }
  g_feat[ch * NPIX + p] = acc;
}

// ---------------- 1x1 conv (OC=256): px-tile 256 x oc-tile 64 ----------------
__global__ __launch_bounds__(256) void kconv1x1(const float* __restrict__ in, int IC,
    const float* __restrict__ w, const float* __restrict__ bias,
    const float* __restrict__ res, int dolrelu, float* __restrict__ out) {
  __shared__ float inT[32 * 256];
  __shared__ float wT[32 * 64];
  const int tid = threadIdx.x;
  const int pxt = blockIdx.x & 63, oct = blockIdx.x >> 6;
  const int pxbase = pxt * 256, ocbase = oct * 64;
  const int pxg = tid & 31, ocg = tid >> 5;
  float acc[8][8];
#pragma unroll
  for (int i = 0; i < 8; ++i)
#pragma unroll
    for (int j = 0; j < 8; ++j) acc[i][j] = 0.f;

#pragma unroll 1
  for (int icc = 0; icc < IC; icc += 32) {
#pragma unroll
    for (int q = 0; q < 8; ++q) {  // stage in [32][256]
      int i4 = tid + q * 256;
      int row = i4 >> 6, c4 = i4 & 63;
      *(float4*)&inT[row * 256 + c4 * 4] = *(const float4*)&in[(size_t)(icc + row) * NPIX + pxbase + c4 * 4];
    }
#pragma unroll
    for (int q = 0; q < 8; ++q) {  // stage w^T [32ic][64oc]
      int e = tid + q * 256;
      int oc = e & 63, ic = e >> 6;
      wT[ic * 64 + oc] = w[(ocbase + oc) * IC + icc + ic];
    }
    __syncthreads();
#pragma unroll 4
    for (int ic = 0; ic < 32; ++ic) {
      float4 i0 = *(const float4*)&inT[ic * 256 + pxg * 8];
      float4 i1 = *(const float4*)&inT[ic * 256 + pxg * 8 + 4];
      float4 w0 = *(const float4*)&wT[ic * 64 + ocg * 8];
      float4 w1 = *(const float4*)&wT[ic * 64 + ocg * 8 + 4];
      float iv[8] = {i0.x, i0.y, i0.z, i0.w, i1.x, i1.y, i1.z, i1.w};
      float wv[8] = {w0.x, w0.y, w0.z, w0.w, w1.x, w1.y, w1.z, w1.w};
#pragma unroll
      for (int i = 0; i < 8; ++i)
#pragma unroll
        for (int j = 0; j < 8; ++j) acc[i][j] += iv[i] * wv[j];
    }
    __syncthreads();
  }
#pragma unroll
  for (int j = 0; j < 8; ++j) {
    const int oc = ocbase + ocg * 8 + j;
    const float bv = bias ? bias[oc] : 0.f;
#pragma unroll
    for (int i = 0; i < 8; ++i) {
      const int px = pxbase + pxg * 8 + i;
      float v = acc[i][j] + bv;
      if (res) v += res[(size_t)oc * NPIX + px];
      if (dolrelu) v = lrelu(v);
      out[(size_t)oc * NPIX + px] = v;
    }
  }
}

// ---------------- 3x3 conv 256->256: 32x32 spatial x 8 oc / block ----------------
__global__ __launch_bounds__(256) void kconv3x3(const float* __restrict__ in,
    const float* __restrict__ w, const float* __restrict__ bias,
    const float* __restrict__ res, const float* __restrict__ modAB, int dolrelu,
    float* __restrict__ out) {
  __shared__ float inT[8 * 34 * 36];  // row stride 36
  __shared__ float wT[576];           // [8oc][8ic][9]
  const int tid = threadIdx.x;
  const int oct = blockIdx.x >> 4;
  const int spt = blockIdx.x & 15;
  const int by = (spt >> 2) * 32, bx = (spt & 3) * 32;
  const int ocbase = oct * 8;
  const int ocq = tid >> 6, ty = (tid >> 3) & 7, tx = tid & 7;
  float acc[2][4][4];
#pragma unroll
  for (int o = 0; o < 2; ++o)
#pragma unroll
    for (int a = 0; a < 4; ++a)
#pragma unroll
      for (int b = 0; b < 4; ++b) acc[o][a][b] = 0.f;

#pragma unroll 1
  for (int icc = 0; icc < 256; icc += 8) {
    for (int e = tid; e < 9248; e += 256) {  // 8 x 34 x 34 halo tile (zero-padded)
      int ic = e / 1156; int r = e - ic * 1156;
      int iy = r / 34; int ix = r - iy * 34;
      int gy = by - 1 + iy, gx = bx - 1 + ix;
      float v = 0.f;
      if (gy >= 0 && gy < 128 && gx >= 0 && gx < 128)
        v = in[(size_t)(icc + ic) * NPIX + gy * 128 + gx];
      inT[ic * 1224 + iy * 36 + ix] = v;
    }
    for (int e = tid; e < 576; e += 256) {
      int oc = e / 72; int r = e - oc * 72;
      wT[e] = w[(ocbase + oc) * 2304 + icc * 9 + r];
    }
    __syncthreads();
#pragma unroll 1
    for (int ic = 0; ic < 8; ++ic) {
      float p[6][8];
#pragma unroll
      for (int rr = 0; rr < 6; ++rr) {
        const float* rp = &inT[ic * 1224 + (ty * 4 + rr) * 36 + tx * 4];
        float4 a = *(const float4*)rp;
        float4 b4 = *(const float4*)(rp + 4);
        p[rr][0] = a.x; p[rr][1] = a.y; p[rr][2] = a.z; p[rr][3] = a.w;
        p[rr][4] = b4.x; p[rr][5] = b4.y; p[rr][6] = b4.z; p[rr][7] = b4.w;
      }
#pragma unroll
      for (int o = 0; o < 2; ++o) {
        const float* wp = &wT[(ocq * 2 + o) * 72 + ic * 9];
        float w9[9];
#pragma unroll
        for (int k = 0; k < 9; ++k) w9[k] = wp[k];
#pragma unroll
        for (int oy = 0; oy < 4; ++oy)
#pragma unroll
          for (int ox = 0; ox < 4; ++ox) {
            float s = acc[o][oy][ox];
#pragma unroll
            for (int ky = 0; ky < 3; ++ky)
#pragma unroll
              for (int kx = 0; kx < 3; ++kx)
                s += w9[ky * 3 + kx] * p[oy + ky][ox + kx];
            acc[o][oy][ox] = s;
          }
      }
    }
    __syncthreads();
  }
#pragma unroll
  for (int o = 0; o < 2; ++o) {
    const int oc = ocbase + ocq * 2 + o;
    const float bv = bias ? bias[oc] : 0.f;
    float ma = 1.f, mb = 0.f;
    if (modAB) { ma = modAB[oc] + 1.f; mb = modAB[256 + oc]; }
#pragma unroll
    for (int oy = 0; oy < 4; ++oy) {
      const int y = by + ty * 4 + oy;
      const int xb = bx + tx * 4;
      float tmp[4];
#pragma unroll
      for (int ox = 0; ox < 4; ++ox) {
        float v = acc[o][oy][ox] + bv;
        if (res) v += res[(size_t)oc * NPIX + y * 128 + xb + ox];
        if (modAB) v = v * ma + mb;
        if (dolrelu) v = lrelu(v);
        tmp[ox] = v;
      }
      float4 vv; vv.x = tmp[0]; vv.y = tmp[1]; vv.z = tmp[2]; vv.w = tmp[3];
      *(float4*)&out[(size_t)oc * NPIX + y * 128 + xb] = vv;
    }
  }
}

// ---------------- final 256->3 conv, fp32 out ----------------
__global__ __launch_bounds__(256) void kfinal(const float* __restrict__ in,
    const float* __restrict__ w, const float* __restrict__ bias, float* __restrict__ outp) {
  const int px = blockIdx.x * 256 + threadIdx.x;
  float a0 = bias[0], a1 = bias[1], a2 = bias[2];
  for (int ic = 0; ic < 256; ++ic) {
    float v = in[(size_t)ic * NPIX + px];
    a0 += v * w[ic];
    a1 += v * w[256 + ic];
    a2 += v * w[512 + ic];
  }
  outp[px] = a0;
  outp[NPIX + px] = a1;
  outp[2 * NPIX + px] = a2;
}

extern "C" void kernel_launch(void* const* d_in, const int* in_sizes, int n_in,
                              void* d_out, int out_size, void* d_ws, size_t ws_size,
                              hipStream_t stream) {
  (void)in_sizes; (void)n_in; (void)out_size; (void)d_ws; (void)ws_size;
  const float* x    = (const float*)d_in[0];
  const float* m    = (const float*)d_in[1];
  const float* z    = (const float*)d_in[2];
  const float* dists= (const float*)d_in[3];
  const float* w1   = (const float*)d_in[4];
  const float* b1   = (const float*)d_in[5];
  const float* wma  = (const float*)d_in[6];
  const float* mlw  = (const float*)d_in[7];
  const float* mlwa = (const float*)d_in[8];
  const float* mlba = (const float*)d_in[9];
  const float* mlwb = (const float*)d_in[10];
  const float* mlbb = (const float*)d_in[11];
  const float* wsig = (const float*)d_in[12];
  const float* bsig = (const float*)d_in[13];
  const float* wc   = (const float*)d_in[14];
  const float* bc   = (const float*)d_in[15];
  const float* wz   = (const float*)d_in[16];
  const float* bz   = (const float*)d_in[17];
  const float* c1w  = (const float*)d_in[18];
  const float* c1b  = (const float*)d_in[19];
  const float* c2aw = (const float*)d_in[20];
  const float* c2ab = (const float*)d_in[21];
  const float* c2bw = (const float*)d_in[22];
  const float* c3aw = (const float*)d_in[23];
  const float* c3ab = (const float*)d_in[24];
  const float* c3bw = (const float*)d_in[25];
  const float* c4aw = (const float*)d_in[26];
  const float* c4ab = (const float*)d_in[27];
  const float* c4bw = (const float*)d_in[28];
  const float* c4bb = (const float*)d_in[29];
  const float* c4w  = (const float*)d_in[30];
  const float* c4b  = (const float*)d_in[31];
  float* outp = (float*)d_out;

  float *pA, *pB, *pC, *pF, *pAmod;
  hipGetSymbolAddress((void**)&pA, HIP_SYMBOL(g_bufA));
  hipGetSymbolAddress((void**)&pB, HIP_SYMBOL(g_bufB));
  hipGetSymbolAddress((void**)&pC, HIP_SYMBOL(g_bufC));
  hipGetSymbolAddress((void**)&pF, HIP_SYMBOL(g_feat));
  hipGetSymbolAddress((void**)&pAmod, HIP_SYMBOL(g_amod));

  kparams<<<1, 256, 0, stream>>>(z, mlwa, mlba, mlwb, mlbb, wz, bz);
  kmlp<<<4096, 256, 0, stream>>>(x, m, w1, b1, wma, mlw, wsig, bsig, wc, bc);
  kcomposite<<<4096, 256, 0, stream>>>(dists);
  // RenderCNN
  kconv1x1<<<256, 256, 0, stream>>>(pF, 64, c1w, c1b, nullptr, 1, pA);                      // y1 = lrelu(c1(feat))
  kconv3x3<<<512, 256, 0, stream>>>(pA, c2aw, c2ab, nullptr, nullptr, 1, pB);               // t = lrelu(c2a(y1))
  kconv3x3<<<512, 256, 0, stream>>>(pB, c2bw, nullptr, pA, pAmod, 1, pC);                   // y2m = lrelu(mod(y1+c2b(t),a0,a1))
  kconv3x3<<<512, 256, 0, stream>>>(pC, c3aw, c3ab, nullptr, nullptr, 1, pA);               // t = lrelu(c3a(y2m))
  kconv3x3<<<512, 256, 0, stream>>>(pA, c3bw, nullptr, pC, pAmod + 512, 1, pB);             // y3m = lrelu(mod(y2m+c3b(t),a2,a3))
  kconv1x1<<<256, 256, 0, stream>>>(pB, 256, c4aw, c4ab, nullptr, 1, pA);                   // t = lrelu(c4a(y3m))
  kconv1x1<<<256, 256, 0, stream>>>(pA, 256, c4bw, c4bb, pB, 1, pC);                        // y4 = lrelu(y3m+c4b(t)+b)
  kfinal<<<64, 256, 0, stream>>>(pC, c4w, c4b, outp);                                       // out = c4(y4)+b
}

// Round 3
// 3193.022 us; speedup vs baseline: 2.2715x; 2.2715x over previous
//
#include <hip/hip_runtime.h>
#include <hip/hip_bf16.h>

#define NPIX 16384          // 128*128
#define S_TOT 262144        // 128*128*16

typedef __attribute__((ext_vector_type(8))) short bf16x8;
typedef __attribute__((ext_vector_type(4))) float f32x4;

__device__ __forceinline__ float lrelu(float v) { return v > 0.f ? v : 0.2f * v; }
__device__ __forceinline__ unsigned short f2b(float f) {
  unsigned u = __float_as_uint(f);
  return (unsigned short)((u + 0x7FFFu + ((u >> 16) & 1u)) >> 16);   // RNE
}
__device__ __forceinline__ unsigned pk2(float a, float b) {
  return (unsigned)f2b(a) | ((unsigned)f2b(b) << 16);
}
__device__ __forceinline__ float b2f(short s) {
  return __uint_as_float(((unsigned)(unsigned short)s) << 16);
}

// ---- device-global scratch (write-before-read each call) ----
__device__ float g_alpha[5 * 256];
__device__ float g_beta[5 * 256];
__device__ float g_amod[1024];          // zc = z@wz^T+bz ; a0|a1|a2|a3
__device__ float g_sigma[S_TOT];
__device__ float g_c[S_TOT * 64];
__device__ float g_feat[64 * NPIX];
__device__ float g_bufA[256 * NPIX];
__device__ float g_bufB[256 * NPIX];
__device__ float g_bufC[256 * NPIX];
// packed bf16 MFMA A-fragments: L1 (K=160) 40960 | 5x ML (K=256) 65536 ea | wc 16384
__device__ short g_wpack[385024];

// ---------------- kparams: z-dependent constants (1 block) ----------------
__global__ __launch_bounds__(256) void kparams(const float* __restrict__ z,
    const float* __restrict__ wa, const float* __restrict__ ba,
    const float* __restrict__ wb, const float* __restrict__ bb,
    const float* __restrict__ wz, const float* __restrict__ bz) {
  __shared__ float zs[256];
  const int t = threadIdx.x;
  zs[t] = z[t];
  __syncthreads();
  for (int l = 0; l < 5; ++l) {
    float accA = ba[l * 256 + t];
    float accB = bb[l * 256 + t];
    const float* rowA = wa + (l * 256 + t) * 256;
    const float* rowB = wb + (l * 256 + t) * 256;
    for (int k = 0; k < 256; k += 4) {
      float4 va = *(const float4*)(rowA + k);
      float4 vb = *(const float4*)(rowB + k);
      accA += va.x * zs[k] + va.y * zs[k + 1] + va.z * zs[k + 2] + va.w * zs[k + 3];
      accB += vb.x * zs[k] + vb.y * zs[k + 1] + vb.z * zs[k + 2] + vb.w * zs[k + 3];
    }
    g_alpha[l * 256 + t] = accA;
    g_beta[l * 256 + t] = accB;
  }
  for (int j = t; j < 1024; j += 256) {
    float acc = bz[j];
    const float* row = wz + j * 256;
    for (int k = 0; k < 256; k += 4) {
      float4 v = *(const float4*)(row + k);
      acc += v.x * zs[k] + v.y * zs[k + 1] + v.z * zs[k + 2] + v.w * zs[k + 3];
    }
    g_amod[j] = acc;
  }
}

// ---------------- kprep: pack weights (alpha-folded) into MFMA A-frag layout ----------------
// A-frag (16x16x32 bf16): lane l holds A[oc = mt*16 + (l&15)][k = ks*32 + (l>>4)*8 + j], j=0..7
// layout: frag (mt,ks) at offset (mt*KSTEPS + ks)*512 + lane*8
__global__ __launch_bounds__(256) void kprep(
    const float* __restrict__ w1, const float* __restrict__ wma,
    const float* __restrict__ mlw, const float* __restrict__ wc) {
  const int idx = blockIdx.x * 256 + threadIdx.x;
  float val;
  if (idx < 40960) {                      // L1: [w1 | wma | 0], K=160, KSTEPS=5
    int mt = idx / 2560, r2 = idx % 2560;
    int ks = r2 / 512, r = r2 % 512;
    int ln = r >> 3, j = r & 7;
    int oc = mt * 16 + (ln & 15);
    int k = ks * 32 + (ln >> 4) * 8 + j;
    val = (k < 128) ? w1[oc * 128 + k] : ((k < 135) ? wma[oc * 7 + (k - 128)] : 0.f);
  } else if (idx < 368640) {              // ML l: W*alpha, K=256, KSTEPS=8
    int t = idx - 40960;
    int l = t / 65536, t2 = t % 65536;
    int mt = t2 / 4096, r2 = t2 % 4096;
    int ks = r2 / 512, r = r2 % 512;
    int ln = r >> 3, j = r & 7;
    int oc = mt * 16 + (ln & 15);
    int k = ks * 32 + (ln >> 4) * 8 + j;
    val = mlw[l * 65536 + oc * 256 + k] * g_alpha[l * 256 + k];
  } else {                                // wc: 64 oc, K=256, KSTEPS=8
    int t = idx - 368640;
    int mt = t / 4096, r2 = t % 4096;
    int ks = r2 / 512, r = r2 % 512;
    int ln = r >> 3, j = r & 7;
    int oc = mt * 16 + (ln & 15);
    int k = ks * 32 + (ln >> 4) * 8 + j;
    val = wc[oc * 256 + k];
  }
  g_wpack[idx] = (short)f2b(val);
}

// ---------------- MFMA MLP: 64 samples / block, 4 waves (each 64 oc x 64 samples) ----------------
// f in LDS: bf16 [64 samples][256 ch], row stride 512 B, XOR swizzle byte ^= (s&7)<<4
__device__ __forceinline__ bf16x8 ldsB(const short* buf, int s, int kbyte) {
  const char* p = (const char*)buf + s * 512 + (kbyte ^ ((s & 7) << 4));
  return *(const bf16x8*)p;
}

template<int KS>
__device__ __forceinline__ void layer_gemm(const short* __restrict__ gA,
    const short* __restrict__ inb, short* __restrict__ outb,
    const float* __restrict__ bias, int lane, int w) {
  const f32x4 zero = {0.f, 0.f, 0.f, 0.f};
  f32x4 acc[4][4];
#pragma unroll
  for (int mi = 0; mi < 4; ++mi)
#pragma unroll
    for (int ni = 0; ni < 4; ++ni) acc[mi][ni] = zero;
  const int lrow = lane & 15;
  const int lkb = (lane >> 4) * 16;       // k byte offset within K-step
#pragma unroll
  for (int ks = 0; ks < KS; ++ks) {
    bf16x8 A[4], B[4];
#pragma unroll
    for (int mi = 0; mi < 4; ++mi)
      A[mi] = *(const bf16x8*)(gA + (size_t)((w * 4 + mi) * KS + ks) * 512 + lane * 8);
#pragma unroll
    for (int ni = 0; ni < 4; ++ni)
      B[ni] = ldsB(inb, ni * 16 + lrow, ks * 64 + lkb);
#pragma unroll
    for (int mi = 0; mi < 4; ++mi)
#pragma unroll
      for (int ni = 0; ni < 4; ++ni)
        acc[mi][ni] = __builtin_amdgcn_mfma_f32_16x16x32_bf16(A[mi], B[ni], acc[mi][ni], 0, 0, 0);
  }
  // epilogue: D col = lane&15 (sample), rows = oc = (lane>>4)*4 + reg
  const int rb = (lane >> 4) * 4;
#pragma unroll
  for (int mi = 0; mi < 4; ++mi) {
    const int oc0 = w * 64 + mi * 16 + rb;
    const float b0 = bias[oc0], b1 = bias[oc0 + 1], b2 = bias[oc0 + 2], b3 = bias[oc0 + 3];
#pragma unroll
    for (int ni = 0; ni < 4; ++ni) {
      const int s = ni * 16 + lrow;
      f32x4 a = acc[mi][ni];
      float v0 = lrelu(a[0] + b0), v1 = lrelu(a[1] + b1);
      float v2 = lrelu(a[2] + b2), v3 = lrelu(a[3] + b3);
      char* p = (char*)outb + s * 512 + ((oc0 * 2) ^ ((s & 7) << 4));
      *(int2*)p = make_int2((int)pk2(v0, v1), (int)pk2(v2, v3));
    }
  }
}

__global__ __launch_bounds__(256, 2) void kmlp_mfma(
    const float* __restrict__ x, const float* __restrict__ m_in,
    const float* __restrict__ b1, const float* __restrict__ bc,
    const float* __restrict__ wsig, const float* __restrict__ bsig) {
  __shared__ short fbuf[2][16384];        // 2 x [64][256] bf16, swizzled
  __shared__ float bias_all[1600];        // b1 | beta0..4 | bc
  __shared__ float wsig_lds[256];
  __shared__ float sred[256];
  const int tid = threadIdx.x;
  const int lane = tid & 63, w = tid >> 6;
  const int s0 = blockIdx.x * 64;

  {  // stage x [64][128] -> fbuf[0] cols 0..127 (bf16, swizzled)
    const float* xp = x + (size_t)s0 * 128;
    const int s = tid >> 2, c = tid & 3;
#pragma unroll
    for (int e = 0; e < 4; ++e) {
      float4 f0 = *(const float4*)(xp + s * 128 + c * 32 + e * 8);
      float4 f1 = *(const float4*)(xp + s * 128 + c * 32 + e * 8 + 4);
      int4 pk;
      pk.x = (int)pk2(f0.x, f0.y); pk.y = (int)pk2(f0.z, f0.w);
      pk.z = (int)pk2(f1.x, f1.y); pk.w = (int)pk2(f1.z, f1.w);
      char* p = (char*)fbuf[0] + s * 512 + ((c * 64 + e * 16) ^ ((s & 7) << 4));
      *(int4*)p = pk;
    }
  }
  if (tid < 64) {  // stage m -> cols 128..159 (7 real + zero pad)
    const float* mp = m_in + (size_t)(s0 + tid) * 7;
    float mv[8];
#pragma unroll
    for (int q = 0; q < 7; ++q) mv[q] = mp[q];
    mv[7] = 0.f;
    int4 pk;
    pk.x = (int)pk2(mv[0], mv[1]); pk.y = (int)pk2(mv[2], mv[3]);
    pk.z = (int)pk2(mv[4], mv[5]); pk.w = (int)pk2(mv[6], mv[7]);
    char* base = (char*)fbuf[0] + tid * 512;
    const int swz = (tid & 7) << 4;
    *(int4*)(base + (256 ^ swz)) = pk;
    int4 zz = make_int4(0, 0, 0, 0);
    *(int4*)(base + (272 ^ swz)) = zz;
    *(int4*)(base + (288 ^ swz)) = zz;
    *(int4*)(base + (304 ^ swz)) = zz;
  }
  bias_all[tid] = b1[tid];
  for (int i = tid; i < 1280; i += 256) bias_all[256 + i] = g_beta[i];
  if (tid < 64) bias_all[1536 + tid] = bc[tid];
  wsig_lds[tid] = wsig[tid];
  __syncthreads();

  layer_gemm<5>(g_wpack,                     fbuf[0], fbuf[1], bias_all,        lane, w);  // L1
  __syncthreads();
  layer_gemm<8>(g_wpack + 40960,             fbuf[1], fbuf[0], bias_all + 256,  lane, w);  // fc_2
  __syncthreads();
  layer_gemm<8>(g_wpack + 40960 + 65536,     fbuf[0], fbuf[1], bias_all + 512,  lane, w);  // fc_3
  __syncthreads();
  layer_gemm<8>(g_wpack + 40960 + 2 * 65536, fbuf[1], fbuf[0], bias_all + 768,  lane, w);  // fc_4
  __syncthreads();
  {  // sigma tap: f(fc_4) . wsig + bsig
    const int s = tid & 63, q = tid >> 6;
    float part = 0.f;
#pragma unroll
    for (int e = 0; e < 8; ++e) {
      bf16x8 v = ldsB(fbuf[0], s, q * 128 + e * 16);
      const float* wp = wsig_lds + q * 64 + e * 8;
#pragma unroll
      for (int j = 0; j < 8; ++j) part += b2f(v[j]) * wp[j];
    }
    sred[q * 64 + s] = part;
  }
  __syncthreads();
  if (tid < 64)
    g_sigma[s0 + tid] = sred[tid] + sred[64 + tid] + sred[128 + tid] + sred[192 + tid] + bsig[0];
  layer_gemm<8>(g_wpack + 40960 + 3 * 65536, fbuf[0], fbuf[1], bias_all + 1024, lane, w);  // fc_5
  __syncthreads();
  layer_gemm<8>(g_wpack + 40960 + 4 * 65536, fbuf[1], fbuf[0], bias_all + 1280, lane, w);  // fc_6
  __syncthreads();
  {  // c = f@wc^T + bc -> g_c fp32 [sample][64]
    const f32x4 zero = {0.f, 0.f, 0.f, 0.f};
    f32x4 acc[4] = {zero, zero, zero, zero};
    const int lrow = lane & 15, lkb = (lane >> 4) * 16;
    const short* gA = g_wpack + 368640;
#pragma unroll
    for (int ks = 0; ks < 8; ++ks) {
      bf16x8 A = *(const bf16x8*)(gA + (size_t)(w * 8 + ks) * 512 + lane * 8);
#pragma unroll
      for (int ni = 0; ni < 4; ++ni) {
        bf16x8 B = ldsB(fbuf[0], ni * 16 + lrow, ks * 64 + lkb);
        acc[ni] = __builtin_amdgcn_mfma_f32_16x16x32_bf16(A, B, acc[ni], 0, 0, 0);
      }
    }
    const int rb = (lane >> 4) * 4;
    const int oc0 = w * 16 + rb;
    const float b0 = bias_all[1536 + oc0], b1v = bias_all[1537 + oc0];
    const float b2v = bias_all[1538 + oc0], b3 = bias_all[1539 + oc0];
#pragma unroll
    for (int ni = 0; ni < 4; ++ni) {
      const int s = ni * 16 + lrow;
      float4 vv;
      vv.x = acc[ni][0] + b0; vv.y = acc[ni][1] + b1v;
      vv.z = acc[ni][2] + b2v; vv.w = acc[ni][3] + b3;
      *(float4*)(g_c + (size_t)(s0 + s) * 64 + oc0) = vv;
    }
  }
}

// ---------------- volumetric compositing: 4 pixels / block ----------------
__global__ __launch_bounds__(256) void kcomposite(const float* __restrict__ dists) {
  const int tid = threadIdx.x;
  const int p = blockIdx.x * 4 + (tid >> 6);
  const int ch = tid & 63;
  const int base = p * 16;
  float T = 1.f, acc = 0.f;
  for (int mm = 0; mm < 16; ++mm) {
    float sgm = g_sigma[base + mm];
    float d = dists[base + mm];
    float a = 1.f - expf(-fmaxf(sgm, 0.f) * d);
    acc += a * T * g_c[(size_t)(base + mm) * 64 + ch];
    T *= (1.f - a + 1e-10f);
  }
  g_feat[ch * NPIX + p] = acc;
}

// ---------------- 1x1 conv (OC=256): px-tile 256 x oc-tile 64 ----------------
__global__ __launch_bounds__(256) void kconv1x1(const float* __restrict__ in, int IC,
    const float* __restrict__ w, const float* __restrict__ bias,
    const float* __restrict__ res, int dolrelu, float* __restrict__ out) {
  __shared__ float inT[32 * 256];
  __shared__ float wT[32 * 64];
  const int tid = threadIdx.x;
  const int pxt = blockIdx.x & 63, oct = blockIdx.x >> 6;
  const int pxbase = pxt * 256, ocbase = oct * 64;
  const int pxg = tid & 31, ocg = tid >> 5;
  float acc[8][8];
#pragma unroll
  for (int i = 0; i < 8; ++i)
#pragma unroll
    for (int j = 0; j < 8; ++j) acc[i][j] = 0.f;

#pragma unroll 1
  for (int icc = 0; icc < IC; icc += 32) {
#pragma unroll
    for (int q = 0; q < 8; ++q) {
      int i4 = tid + q * 256;
      int row = i4 >> 6, c4 = i4 & 63;
      *(float4*)&inT[row * 256 + c4 * 4] = *(const float4*)&in[(size_t)(icc + row) * NPIX + pxbase + c4 * 4];
    }
#pragma unroll
    for (int q = 0; q < 8; ++q) {
      int e = tid + q * 256;
      int oc = e & 63, ic = e >> 6;
      wT[ic * 64 + oc] = w[(ocbase + oc) * IC + icc + ic];
    }
    __syncthreads();
#pragma unroll 4
    for (int ic = 0; ic < 32; ++ic) {
      float4 i0 = *(const float4*)&inT[ic * 256 + pxg * 8];
      float4 i1 = *(const float4*)&inT[ic * 256 + pxg * 8 + 4];
      float4 w0 = *(const float4*)&wT[ic * 64 + ocg * 8];
      float4 w1 = *(const float4*)&wT[ic * 64 + ocg * 8 + 4];
      float iv[8] = {i0.x, i0.y, i0.z, i0.w, i1.x, i1.y, i1.z, i1.w};
      float wv[8] = {w0.x, w0.y, w0.z, w0.w, w1.x, w1.y, w1.z, w1.w};
#pragma unroll
      for (int i = 0; i < 8; ++i)
#pragma unroll
        for (int j = 0; j < 8; ++j) acc[i][j] += iv[i] * wv[j];
    }
    __syncthreads();
  }
#pragma unroll
  for (int j = 0; j < 8; ++j) {
    const int oc = ocbase + ocg * 8 + j;
    const float bv = bias ? bias[oc] : 0.f;
#pragma unroll
    for (int i = 0; i < 8; ++i) {
      const int px = pxbase + pxg * 8 + i;
      float v = acc[i][j] + bv;
      if (res) v += res[(size_t)oc * NPIX + px];
      if (dolrelu) v = lrelu(v);
      out[(size_t)oc * NPIX + px] = v;
    }
  }
}

// ---------------- 3x3 conv 256->256: 32x32 spatial x 8 oc / block ----------------
__global__ __launch_bounds__(256) void kconv3x3(const float* __restrict__ in,
    const float* __restrict__ w, const float* __restrict__ bias,
    const float* __restrict__ res, const float* __restrict__ modAB, int dolrelu,
    float* __restrict__ out) {
  __shared__ float inT[8 * 34 * 36];
  __shared__ float wT[576];
  const int tid = threadIdx.x;
  const int oct = blockIdx.x >> 4;
  const int spt = blockIdx.x & 15;
  const int by = (spt >> 2) * 32, bx = (spt & 3) * 32;
  const int ocbase = oct * 8;
  const int ocq = tid >> 6, ty = (tid >> 3) & 7, tx = tid & 7;
  float acc[2][4][4];
#pragma unroll
  for (int o = 0; o < 2; ++o)
#pragma unroll
    for (int a = 0; a < 4; ++a)
#pragma unroll
      for (int b = 0; b < 4; ++b) acc[o][a][b] = 0.f;

#pragma unroll 1
  for (int icc = 0; icc < 256; icc += 8) {
    for (int e = tid; e < 9248; e += 256) {
      int ic = e / 1156; int r = e - ic * 1156;
      int iy = r / 34; int ix = r - iy * 34;
      int gy = by - 1 + iy, gx = bx - 1 + ix;
      float v = 0.f;
      if (gy >= 0 && gy < 128 && gx >= 0 && gx < 128)
        v = in[(size_t)(icc + ic) * NPIX + gy * 128 + gx];
      inT[ic * 1224 + iy * 36 + ix] = v;
    }
    for (int e = tid; e < 576; e += 256) {
      int oc = e / 72; int r = e - oc * 72;
      wT[e] = w[(ocbase + oc) * 2304 + icc * 9 + r];
    }
    __syncthreads();
#pragma unroll 1
    for (int ic = 0; ic < 8; ++ic) {
      float p[6][8];
#pragma unroll
      for (int rr = 0; rr < 6; ++rr) {
        const float* rp = &inT[ic * 1224 + (ty * 4 + rr) * 36 + tx * 4];
        float4 a = *(const float4*)rp;
        float4 b4 = *(const float4*)(rp + 4);
        p[rr][0] = a.x; p[rr][1] = a.y; p[rr][2] = a.z; p[rr][3] = a.w;
        p[rr][4] = b4.x; p[rr][5] = b4.y; p[rr][6] = b4.z; p[rr][7] = b4.w;
      }
#pragma unroll
      for (int o = 0; o < 2; ++o) {
        const float* wp = &wT[(ocq * 2 + o) * 72 + ic * 9];
        float w9[9];
#pragma unroll
        for (int k = 0; k < 9; ++k) w9[k] = wp[k];
#pragma unroll
        for (int oy = 0; oy < 4; ++oy)
#pragma unroll
          for (int ox = 0; ox < 4; ++ox) {
            float s = acc[o][oy][ox];
#pragma unroll
            for (int ky = 0; ky < 3; ++ky)
#pragma unroll
              for (int kx = 0; kx < 3; ++kx)
                s += w9[ky * 3 + kx] * p[oy + ky][ox + kx];
            acc[o][oy][ox] = s;
          }
      }
    }
    __syncthreads();
  }
#pragma unroll
  for (int o = 0; o < 2; ++o) {
    const int oc = ocbase + ocq * 2 + o;
    const float bv = bias ? bias[oc] : 0.f;
    float ma = 1.f, mb = 0.f;
    if (modAB) { ma = modAB[oc] + 1.f; mb = modAB[256 + oc]; }
#pragma unroll
    for (int oy = 0; oy < 4; ++oy) {
      const int y = by + ty * 4 + oy;
      const int xb = bx + tx * 4;
      float tmp[4];
#pragma unroll
      for (int ox = 0; ox < 4; ++ox) {
        float v = acc[o][oy][ox] + bv;
        if (res) v += res[(size_t)oc * NPIX + y * 128 + xb + ox];
        if (modAB) v = v * ma + mb;
        if (dolrelu) v = lrelu(v);
        tmp[ox] = v;
      }
      float4 vv; vv.x = tmp[0]; vv.y = tmp[1]; vv.z = tmp[2]; vv.w = tmp[3];
      *(float4*)&out[(size_t)oc * NPIX + y * 128 + xb] = vv;
    }
  }
}

// ---------------- final 256->3 conv, fp32 out ----------------
__global__ __launch_bounds__(256) void kfinal(const float* __restrict__ in,
    const float* __restrict__ w, const float* __restrict__ bias, float* __restrict__ outp) {
  const int px = blockIdx.x * 256 + threadIdx.x;
  float a0 = bias[0], a1 = bias[1], a2 = bias[2];
  for (int ic = 0; ic < 256; ++ic) {
    float v = in[(size_t)ic * NPIX + px];
    a0 += v * w[ic];
    a1 += v * w[256 + ic];
    a2 += v * w[512 + ic];
  }
  outp[px] = a0;
  outp[NPIX + px] = a1;
  outp[2 * NPIX + px] = a2;
}

extern "C" void kernel_launch(void* const* d_in, const int* in_sizes, int n_in,
                              void* d_out, int out_size, void* d_ws, size_t ws_size,
                              hipStream_t stream) {
  (void)in_sizes; (void)n_in; (void)out_size; (void)d_ws; (void)ws_size;
  const float* x    = (const float*)d_in[0];
  const float* m    = (const float*)d_in[1];
  const float* z    = (const float*)d_in[2];
  const float* dists= (const float*)d_in[3];
  const float* w1   = (const float*)d_in[4];
  const float* b1   = (const float*)d_in[5];
  const float* wma  = (const float*)d_in[6];
  const float* mlw  = (const float*)d_in[7];
  const float* mlwa = (const float*)d_in[8];
  const float* mlba = (const float*)d_in[9];
  const float* mlwb = (const float*)d_in[10];
  const float* mlbb = (const float*)d_in[11];
  const float* wsig = (const float*)d_in[12];
  const float* bsig = (const float*)d_in[13];
  const float* wc   = (const float*)d_in[14];
  const float* bc   = (const float*)d_in[15];
  const float* wz   = (const float*)d_in[16];
  const float* bz   = (const float*)d_in[17];
  const float* c1w  = (const float*)d_in[18];
  const float* c1b  = (const float*)d_in[19];
  const float* c2aw = (const float*)d_in[20];
  const float* c2ab = (const float*)d_in[21];
  const float* c2bw = (const float*)d_in[22];
  const float* c3aw = (const float*)d_in[23];
  const float* c3ab = (const float*)d_in[24];
  const float* c3bw = (const float*)d_in[25];
  const float* c4aw = (const float*)d_in[26];
  const float* c4ab = (const float*)d_in[27];
  const float* c4bw = (const float*)d_in[28];
  const float* c4bb = (const float*)d_in[29];
  const float* c4w  = (const float*)d_in[30];
  const float* c4b  = (const float*)d_in[31];
  float* outp = (float*)d_out;

  float *pA, *pB, *pC, *pF, *pAmod;
  hipGetSymbolAddress((void**)&pA, HIP_SYMBOL(g_bufA));
  hipGetSymbolAddress((void**)&pB, HIP_SYMBOL(g_bufB));
  hipGetSymbolAddress((void**)&pC, HIP_SYMBOL(g_bufC));
  hipGetSymbolAddress((void**)&pF, HIP_SYMBOL(g_feat));
  hipGetSymbolAddress((void**)&pAmod, HIP_SYMBOL(g_amod));

  kparams<<<1, 256, 0, stream>>>(z, mlwa, mlba, mlwb, mlbb, wz, bz);
  kprep<<<1504, 256, 0, stream>>>(w1, wma, mlw, wc);
  kmlp_mfma<<<4096, 256, 0, stream>>>(x, m, b1, bc, wsig, bsig);
  kcomposite<<<4096, 256, 0, stream>>>(dists);
  // RenderCNN
  kconv1x1<<<256, 256, 0, stream>>>(pF, 64, c1w, c1b, nullptr, 1, pA);
  kconv3x3<<<512, 256, 0, stream>>>(pA, c2aw, c2ab, nullptr, nullptr, 1, pB);
  kconv3x3<<<512, 256, 0, stream>>>(pB, c2bw, nullptr, pA, pAmod, 1, pC);
  kconv3x3<<<512, 256, 0, stream>>>(pC, c3aw, c3ab, nullptr, nullptr, 1, pA);
  kconv3x3<<<512, 256, 0, stream>>>(pA, c3bw, nullptr, pC, pAmod + 512, 1, pB);
  kconv1x1<<<256, 256, 0, stream>>>(pB, 256, c4aw, c4ab, nullptr, 1, pA);
  kconv1x1<<<256, 256, 0, stream>>>(pA, 256, c4bw, c4bb, pB, 1, pC);
  kfinal<<<64, 256, 0, stream>>>(pC, c4w, c4b, outp);
}

// Round 4
// 632.088 us; speedup vs baseline: 11.4747x; 5.0515x over previous
//
#include <hip/hip_runtime.h>
#include <hip/hip_bf16.h>

#define NPIX 16384          // 128*128
#define S_TOT 262144        // 128*128*16

typedef __attribute__((ext_vector_type(8))) short bf16x8;
typedef __attribute__((ext_vector_type(4))) float f32x4;

__device__ __forceinline__ float lrelu(float v) { return v > 0.f ? v : 0.2f * v; }
__device__ __forceinline__ unsigned short f2b(float f) {
  unsigned u = __float_as_uint(f);
  return (unsigned short)((u + 0x7FFFu + ((u >> 16) & 1u)) >> 16);   // RNE
}
__device__ __forceinline__ unsigned pk2(float a, float b) {
  return (unsigned)f2b(a) | ((unsigned)f2b(b) << 16);
}
__device__ __forceinline__ float b2f(short s) {
  return __uint_as_float(((unsigned)(unsigned short)s) << 16);
}
__device__ __forceinline__ float f_lo(int u) { return __uint_as_float((unsigned)u << 16); }
__device__ __forceinline__ float f_hi(int u) { return __uint_as_float((unsigned)u & 0xffff0000u); }

// ---- device-global scratch (write-before-read each call) ----
__device__ float g_alpha[5 * 256];
__device__ float g_beta[5 * 256];
__device__ float g_amod[1024];          // zc = z@wz^T+bz ; a0|a1|a2|a3
__device__ float g_sigma[S_TOT];
__device__ float g_c[S_TOT * 64];       // fp32 (error budget)
__device__ short g_featb[NPIX * 64];    // bf16 [px][64]
__device__ short g_y1[NPIX * 256];      // bf16 [px][256]
__device__ short g_y2[NPIX * 256];
__device__ short g_y3[NPIX * 256];
__device__ short g_t [NPIX * 256];
// MLP packed A-frags: L1 (K=160) 40960 | 5x ML (K=256) 65536 ea | wc 16384
__device__ short g_wpack[385024];
// CNN packed A-frags: c1(16384) | c2a,c2b,c3a,c3b (589824 ea) | c4a,c4b (65536 ea)
#define O_C1  0
#define O_C2A 16384
#define O_C2B (16384 + 589824)
#define O_C3A (16384 + 2 * 589824)
#define O_C3B (16384 + 3 * 589824)
#define O_C4A (16384 + 4 * 589824)
#define O_C4B (16384 + 4 * 589824 + 65536)
__device__ short g_wpack2[2506752];

// ---------------- kparams: z-dependent constants (1 block) ----------------
__global__ __launch_bounds__(256) void kparams(const float* __restrict__ z,
    const float* __restrict__ wa, const float* __restrict__ ba,
    const float* __restrict__ wb, const float* __restrict__ bb,
    const float* __restrict__ wz, const float* __restrict__ bz) {
  __shared__ float zs[256];
  const int t = threadIdx.x;
  zs[t] = z[t];
  __syncthreads();
  for (int l = 0; l < 5; ++l) {
    float accA = ba[l * 256 + t];
    float accB = bb[l * 256 + t];
    const float* rowA = wa + (l * 256 + t) * 256;
    const float* rowB = wb + (l * 256 + t) * 256;
    for (int k = 0; k < 256; k += 4) {
      float4 va = *(const float4*)(rowA + k);
      float4 vb = *(const float4*)(rowB + k);
      accA += va.x * zs[k] + va.y * zs[k + 1] + va.z * zs[k + 2] + va.w * zs[k + 3];
      accB += vb.x * zs[k] + vb.y * zs[k + 1] + vb.z * zs[k + 2] + vb.w * zs[k + 3];
    }
    g_alpha[l * 256 + t] = accA;
    g_beta[l * 256 + t] = accB;
  }
  for (int j = t; j < 1024; j += 256) {
    float acc = bz[j];
    const float* row = wz + j * 256;
    for (int k = 0; k < 256; k += 4) {
      float4 v = *(const float4*)(row + k);
      acc += v.x * zs[k] + v.y * zs[k + 1] + v.z * zs[k + 2] + v.w * zs[k + 3];
    }
    g_amod[j] = acc;
  }
}

// ---------------- kprep: pack MLP weights (alpha-folded) into MFMA A-frag layout ----------------
// A-frag (16x16x32 bf16): lane l holds A[oc = mt*16 + (l&15)][k = ks*32 + (l>>4)*8 + j], j=0..7
__global__ __launch_bounds__(256) void kprep(
    const float* __restrict__ w1, const float* __restrict__ wma,
    const float* __restrict__ mlw, const float* __restrict__ wc) {
  const int idx = blockIdx.x * 256 + threadIdx.x;
  float val;
  if (idx < 40960) {                      // L1: [w1 | wma | 0], K=160, KSTEPS=5
    int mt = idx / 2560, r2 = idx % 2560;
    int ks = r2 / 512, r = r2 % 512;
    int ln = r >> 3, j = r & 7;
    int oc = mt * 16 + (ln & 15);
    int k = ks * 32 + (ln >> 4) * 8 + j;
    val = (k < 128) ? w1[oc * 128 + k] : ((k < 135) ? wma[oc * 7 + (k - 128)] : 0.f);
  } else if (idx < 368640) {              // ML l: W*alpha, K=256, KSTEPS=8
    int t = idx - 40960;
    int l = t / 65536, t2 = t % 65536;
    int mt = t2 / 4096, r2 = t2 % 4096;
    int ks = r2 / 512, r = r2 % 512;
    int ln = r >> 3, j = r & 7;
    int oc = mt * 16 + (ln & 15);
    int k = ks * 32 + (ln >> 4) * 8 + j;
    val = mlw[l * 65536 + oc * 256 + k] * g_alpha[l * 256 + k];
  } else {                                // wc: 64 oc, K=256, KSTEPS=8
    int t = idx - 368640;
    int mt = t / 4096, r2 = t % 4096;
    int ks = r2 / 512, r = r2 % 512;
    int ln = r >> 3, j = r & 7;
    int oc = mt * 16 + (ln & 15);
    int k = ks * 32 + (ln >> 4) * 8 + j;
    val = wc[oc * 256 + k];
  }
  g_wpack[idx] = (short)f2b(val);
}

// ---------------- kprep_cnn: pack CNN weights into A-frag layout ----------------
__global__ __launch_bounds__(256) void kprep_cnn(
    const float* __restrict__ c1w,
    const float* __restrict__ c2aw, const float* __restrict__ c2bw,
    const float* __restrict__ c3aw, const float* __restrict__ c3bw,
    const float* __restrict__ c4aw, const float* __restrict__ c4bw) {
  const int idx = blockIdx.x * 256 + threadIdx.x;
  float val;
  if (idx < 16384) {                       // c1: 256 oc x 64 ic, KS=2
    int mt = idx / 1024, r2 = idx % 1024;
    int ks = r2 / 512, r = r2 % 512;
    int ln = r >> 3, j = r & 7;
    int oc = mt * 16 + (ln & 15);
    int k = ks * 32 + (ln >> 4) * 8 + j;
    val = c1w[oc * 64 + k];
  } else if (idx < O_C4A) {                // 3x3 convs: K = tap*256 + ic, KS=72
    int t = idx - 16384;
    int cv = t / 589824, t2 = t % 589824;
    const float* w = (cv == 0) ? c2aw : (cv == 1) ? c2bw : (cv == 2) ? c3aw : c3bw;
    int mt = t2 / 36864, r2 = t2 % 36864;
    int ks = r2 / 512, r = r2 % 512;
    int ln = r >> 3, j = r & 7;
    int oc = mt * 16 + (ln & 15);
    int k = ks * 32 + (ln >> 4) * 8 + j;
    int tap = k >> 8, ic = k & 255;
    val = w[oc * 2304 + ic * 9 + tap];
  } else {                                 // c4a / c4b: 256x256, KS=8
    int t = idx - O_C4A;
    const float* w = (t < 65536) ? c4aw : c4bw;
    int t2 = t & 65535;
    int mt = t2 / 4096, r2 = t2 % 4096;
    int ks = r2 / 512, r = r2 % 512;
    int ln = r >> 3, j = r & 7;
    int oc = mt * 16 + (ln & 15);
    int k = ks * 32 + (ln >> 4) * 8 + j;
    val = w[oc * 256 + k];
  }
  g_wpack2[idx] = (short)f2b(val);
}

// ---------------- MFMA MLP: 64 samples / block, 4 waves ----------------
__device__ __forceinline__ bf16x8 ldsB(const short* buf, int s, int kbyte) {
  const char* p = (const char*)buf + s * 512 + (kbyte ^ ((s & 7) << 4));
  return *(const bf16x8*)p;
}

template<int KS>
__device__ __forceinline__ void layer_gemm(const short* __restrict__ gA,
    const short* __restrict__ inb, short* __restrict__ outb,
    const float* __restrict__ bias, int lane, int w) {
  const f32x4 zero = {0.f, 0.f, 0.f, 0.f};
  f32x4 acc[4][4];
#pragma unroll
  for (int mi = 0; mi < 4; ++mi)
#pragma unroll
    for (int ni = 0; ni < 4; ++ni) acc[mi][ni] = zero;
  const int lrow = lane & 15;
  const int lkb = (lane >> 4) * 16;
#pragma unroll
  for (int ks = 0; ks < KS; ++ks) {
    bf16x8 A[4], B[4];
#pragma unroll
    for (int mi = 0; mi < 4; ++mi)
      A[mi] = *(const bf16x8*)(gA + (size_t)((w * 4 + mi) * KS + ks) * 512 + lane * 8);
#pragma unroll
    for (int ni = 0; ni < 4; ++ni)
      B[ni] = ldsB(inb, ni * 16 + lrow, ks * 64 + lkb);
#pragma unroll
    for (int mi = 0; mi < 4; ++mi)
#pragma unroll
      for (int ni = 0; ni < 4; ++ni)
        acc[mi][ni] = __builtin_amdgcn_mfma_f32_16x16x32_bf16(A[mi], B[ni], acc[mi][ni], 0, 0, 0);
  }
  const int rb = (lane >> 4) * 4;
#pragma unroll
  for (int mi = 0; mi < 4; ++mi) {
    const int oc0 = w * 64 + mi * 16 + rb;
    const float b0 = bias[oc0], b1 = bias[oc0 + 1], b2 = bias[oc0 + 2], b3 = bias[oc0 + 3];
#pragma unroll
    for (int ni = 0; ni < 4; ++ni) {
      const int s = ni * 16 + lrow;
      f32x4 a = acc[mi][ni];
      float v0 = lrelu(a[0] + b0), v1 = lrelu(a[1] + b1);
      float v2 = lrelu(a[2] + b2), v3 = lrelu(a[3] + b3);
      char* p = (char*)outb + s * 512 + ((oc0 * 2) ^ ((s & 7) << 4));
      *(int2*)p = make_int2((int)pk2(v0, v1), (int)pk2(v2, v3));
    }
  }
}

__global__ __launch_bounds__(256, 2) void kmlp_mfma(
    const float* __restrict__ x, const float* __restrict__ m_in,
    const float* __restrict__ b1, const float* __restrict__ bc,
    const float* __restrict__ wsig, const float* __restrict__ bsig) {
  __shared__ short fbuf[2][16384];
  __shared__ float bias_all[1600];
  __shared__ float wsig_lds[256];
  __shared__ float sred[256];
  const int tid = threadIdx.x;
  const int lane = tid & 63, w = tid >> 6;
  const int s0 = blockIdx.x * 64;

  {
    const float* xp = x + (size_t)s0 * 128;
    const int s = tid >> 2, c = tid & 3;
#pragma unroll
    for (int e = 0; e < 4; ++e) {
      float4 f0 = *(const float4*)(xp + s * 128 + c * 32 + e * 8);
      float4 f1 = *(const float4*)(xp + s * 128 + c * 32 + e * 8 + 4);
      int4 pk;
      pk.x = (int)pk2(f0.x, f0.y); pk.y = (int)pk2(f0.z, f0.w);
      pk.z = (int)pk2(f1.x, f1.y); pk.w = (int)pk2(f1.z, f1.w);
      char* p = (char*)fbuf[0] + s * 512 + ((c * 64 + e * 16) ^ ((s & 7) << 4));
      *(int4*)p = pk;
    }
  }
  if (tid < 64) {
    const float* mp = m_in + (size_t)(s0 + tid) * 7;
    float mv[8];
#pragma unroll
    for (int q = 0; q < 7; ++q) mv[q] = mp[q];
    mv[7] = 0.f;
    int4 pk;
    pk.x = (int)pk2(mv[0], mv[1]); pk.y = (int)pk2(mv[2], mv[3]);
    pk.z = (int)pk2(mv[4], mv[5]); pk.w = (int)pk2(mv[6], mv[7]);
    char* base = (char*)fbuf[0] + tid * 512;
    const int swz = (tid & 7) << 4;
    *(int4*)(base + (256 ^ swz)) = pk;
    int4 zz = make_int4(0, 0, 0, 0);
    *(int4*)(base + (272 ^ swz)) = zz;
    *(int4*)(base + (288 ^ swz)) = zz;
    *(int4*)(base + (304 ^ swz)) = zz;
  }
  bias_all[tid] = b1[tid];
  for (int i = tid; i < 1280; i += 256) bias_all[256 + i] = g_beta[i];
  if (tid < 64) bias_all[1536 + tid] = bc[tid];
  wsig_lds[tid] = wsig[tid];
  __syncthreads();

  layer_gemm<5>(g_wpack,                     fbuf[0], fbuf[1], bias_all,        lane, w);
  __syncthreads();
  layer_gemm<8>(g_wpack + 40960,             fbuf[1], fbuf[0], bias_all + 256,  lane, w);
  __syncthreads();
  layer_gemm<8>(g_wpack + 40960 + 65536,     fbuf[0], fbuf[1], bias_all + 512,  lane, w);
  __syncthreads();
  layer_gemm<8>(g_wpack + 40960 + 2 * 65536, fbuf[1], fbuf[0], bias_all + 768,  lane, w);
  __syncthreads();
  {
    const int s = tid & 63, q = tid >> 6;
    float part = 0.f;
#pragma unroll
    for (int e = 0; e < 8; ++e) {
      bf16x8 v = ldsB(fbuf[0], s, q * 128 + e * 16);
      const float* wp = wsig_lds + q * 64 + e * 8;
#pragma unroll
      for (int j = 0; j < 8; ++j) part += b2f(v[j]) * wp[j];
    }
    sred[q * 64 + s] = part;
  }
  __syncthreads();
  if (tid < 64)
    g_sigma[s0 + tid] = sred[tid] + sred[64 + tid] + sred[128 + tid] + sred[192 + tid] + bsig[0];
  layer_gemm<8>(g_wpack + 40960 + 3 * 65536, fbuf[0], fbuf[1], bias_all + 1024, lane, w);
  __syncthreads();
  layer_gemm<8>(g_wpack + 40960 + 4 * 65536, fbuf[1], fbuf[0], bias_all + 1280, lane, w);
  __syncthreads();
  {  // c = f@wc^T + bc -> g_c fp32 [sample][64]
    const f32x4 zero = {0.f, 0.f, 0.f, 0.f};
    f32x4 acc[4] = {zero, zero, zero, zero};
    const int lrow = lane & 15, lkb = (lane >> 4) * 16;
    const short* gA = g_wpack + 368640;
#pragma unroll
    for (int ks = 0; ks < 8; ++ks) {
      bf16x8 A = *(const bf16x8*)(gA + (size_t)(w * 8 + ks) * 512 + lane * 8);
#pragma unroll
      for (int ni = 0; ni < 4; ++ni) {
        bf16x8 B = ldsB(fbuf[0], ni * 16 + lrow, ks * 64 + lkb);
        acc[ni] = __builtin_amdgcn_mfma_f32_16x16x32_bf16(A, B, acc[ni], 0, 0, 0);
      }
    }
    const int rb = (lane >> 4) * 4;
    const int oc0 = w * 16 + rb;
    const float b0 = bias_all[1536 + oc0], b1v = bias_all[1537 + oc0];
    const float b2v = bias_all[1538 + oc0], b3 = bias_all[1539 + oc0];
#pragma unroll
    for (int ni = 0; ni < 4; ++ni) {
      const int s = ni * 16 + lrow;
      float4 vv;
      vv.x = acc[ni][0] + b0; vv.y = acc[ni][1] + b1v;
      vv.z = acc[ni][2] + b2v; vv.w = acc[ni][3] + b3;
      *(float4*)(g_c + (size_t)(s0 + s) * 64 + oc0) = vv;
    }
  }
}

// ---------------- volumetric compositing -> bf16 feat [px][64] ----------------
__global__ __launch_bounds__(256) void kcomposite(const float* __restrict__ dists) {
  const int tid = threadIdx.x;
  const int p = blockIdx.x * 4 + (tid >> 6);
  const int ch = tid & 63;
  const int base = p * 16;
  float T = 1.f, acc = 0.f;
  for (int mm = 0; mm < 16; ++mm) {
    float sgm = g_sigma[base + mm];
    float d = dists[base + mm];
    float a = 1.f - expf(-fmaxf(sgm, 0.f) * d);
    acc += a * T * g_c[(size_t)(base + mm) * 64 + ch];
    T *= (1.f - a + 1e-10f);
  }
  g_featb[p * 64 + ch] = (short)f2b(acc);
}

// ---------------- MFMA 1x1 conv: 32 px x 256 oc / block, 4 waves ----------------
template<int IC>
__global__ __launch_bounds__(256, 2) void kgemm1x1(const short* __restrict__ in,
    const short* __restrict__ gA, const float* __restrict__ bias,
    const short* __restrict__ res, int domod, const float* __restrict__ modAB,
    short* __restrict__ out) {
  constexpr int KS = IC / 32;
  constexpr int ROWB = IC * 2;
  __shared__ short binb[32 * IC];
  const int tid = threadIdx.x;
  const int lane = tid & 63, w = tid >> 6;
  const int px0 = blockIdx.x * 32;

  for (int e = tid; e < 32 * IC / 8; e += 256) {
    const int px = e / (IC / 8), lg = e % (IC / 8);
    bf16x8 v = *(const bf16x8*)(in + (size_t)(px0 + px) * IC + lg * 8);
    char* p = (char*)binb + px * ROWB + ((lg * 16) ^ ((px & 7) << 4));
    *(bf16x8*)p = v;
  }
  __syncthreads();

  const f32x4 zero = {0.f, 0.f, 0.f, 0.f};
  f32x4 acc[4][2];
#pragma unroll
  for (int mi = 0; mi < 4; ++mi)
#pragma unroll
    for (int ni = 0; ni < 2; ++ni) acc[mi][ni] = zero;
  const int lrow = lane & 15;
  const int lkb = (lane >> 4) * 16;
#pragma unroll
  for (int ks = 0; ks < KS; ++ks) {
    bf16x8 A[4], B[2];
#pragma unroll
    for (int mi = 0; mi < 4; ++mi)
      A[mi] = *(const bf16x8*)(gA + (size_t)((w * 4 + mi) * KS + ks) * 512 + lane * 8);
#pragma unroll
    for (int ni = 0; ni < 2; ++ni) {
      const int s = ni * 16 + lrow;
      const char* p = (const char*)binb + s * ROWB + ((ks * 64 + lkb) ^ ((s & 7) << 4));
      B[ni] = *(const bf16x8*)p;
    }
#pragma unroll
    for (int mi = 0; mi < 4; ++mi)
#pragma unroll
      for (int ni = 0; ni < 2; ++ni)
        acc[mi][ni] = __builtin_amdgcn_mfma_f32_16x16x32_bf16(A[mi], B[ni], acc[mi][ni], 0, 0, 0);
  }
  const int rb = (lane >> 4) * 4;
#pragma unroll
  for (int mi = 0; mi < 4; ++mi) {
    const int oc = w * 64 + mi * 16 + rb;
    float bv[4] = {0.f, 0.f, 0.f, 0.f};
    if (bias) { bv[0] = bias[oc]; bv[1] = bias[oc + 1]; bv[2] = bias[oc + 2]; bv[3] = bias[oc + 3]; }
#pragma unroll
    for (int ni = 0; ni < 2; ++ni) {
      const int gpx = px0 + ni * 16 + lrow;
      f32x4 a = acc[mi][ni];
      float v[4];
#pragma unroll
      for (int r = 0; r < 4; ++r) v[r] = a[r] + bv[r];
      if (res) {
        int2 rv = *(const int2*)(res + (size_t)gpx * 256 + oc);
        v[0] += f_lo(rv.x); v[1] += f_hi(rv.x); v[2] += f_lo(rv.y); v[3] += f_hi(rv.y);
      }
      if (domod) {
#pragma unroll
        for (int r = 0; r < 4; ++r) v[r] = v[r] * (modAB[oc + r] + 1.f) + modAB[256 + oc + r];
      }
#pragma unroll
      for (int r = 0; r < 4; ++r) v[r] = lrelu(v[r]);
      *(int2*)(out + (size_t)gpx * 256 + oc) = make_int2((int)pk2(v[0], v[1]), (int)pk2(v[2], v[3]));
    }
  }
}

// ---------------- MFMA 3x3 conv: 128 oc x 64 px (2x32) / block ----------------
__global__ __launch_bounds__(256, 2) void kconv3(const short* __restrict__ in,
    const short* __restrict__ gA, const float* __restrict__ bias,
    const short* __restrict__ res, int domod, const float* __restrict__ modAB,
    short* __restrict__ out) {
  __shared__ short halo[136 * 64];        // [4x34 spatial][64 ic], row 128B, swizzled
  const int tid = threadIdx.x;
  const int lane = tid & 63, w = tid >> 6;
  const int oct = blockIdx.x >> 8;
  const int pxt = blockIdx.x & 255;
  const int x0 = (pxt & 3) * 32, y0 = (pxt >> 2) * 2;
  const int oc0 = oct * 128 + w * 32;
  const int lrow = lane & 15;
  const int lkb = (lane >> 4) * 16;

  const f32x4 zero = {0.f, 0.f, 0.f, 0.f};
  f32x4 acc[2][4];
#pragma unroll
  for (int mi = 0; mi < 2; ++mi)
#pragma unroll
    for (int ni = 0; ni < 4; ++ni) acc[mi][ni] = zero;

#pragma unroll 1
  for (int c = 0; c < 4; ++c) {
    for (int e = tid; e < 1088; e += 256) {
      const int row = e >> 3, lg = e & 7;
      const int yy = row / 34, xx = row - yy * 34;
      const int gy = y0 - 1 + yy, gx = x0 - 1 + xx;
      bf16x8 v = {0, 0, 0, 0, 0, 0, 0, 0};
      if (gy >= 0 && gy < 128 && gx >= 0 && gx < 128)
        v = *(const bf16x8*)(in + (size_t)((gy << 7) + gx) * 256 + c * 64 + lg * 8);
      char* p = (char*)halo + row * 128 + ((lg * 16) ^ ((row & 7) << 4));
      *(bf16x8*)p = v;
    }
    __syncthreads();
#pragma unroll
    for (int tap = 0; tap < 9; ++tap) {
      const int ky = tap / 3, kx = tap - ky * 3;
#pragma unroll
      for (int s = 0; s < 2; ++s) {
        const int ksg = tap * 8 + c * 2 + s;
        bf16x8 A[2], B[4];
#pragma unroll
        for (int mi = 0; mi < 2; ++mi)
          A[mi] = *(const bf16x8*)(gA + (size_t)(((oct * 8 + w * 2 + mi) * 72 + ksg)) * 512 + lane * 8);
#pragma unroll
        for (int ni = 0; ni < 4; ++ni) {
          const int p = ni * 16 + lrow;
          const int row = ((p >> 5) + ky) * 34 + (p & 31) + kx;
          const char* bp = (const char*)halo + row * 128 + ((s * 64 + lkb) ^ ((row & 7) << 4));
          B[ni] = *(const bf16x8*)bp;
        }
#pragma unroll
        for (int mi = 0; mi < 2; ++mi)
#pragma unroll
          for (int ni = 0; ni < 4; ++ni)
            acc[mi][ni] = __builtin_amdgcn_mfma_f32_16x16x32_bf16(A[mi], B[ni], acc[mi][ni], 0, 0, 0);
      }
    }
    __syncthreads();
  }

  const int rb = (lane >> 4) * 4;
#pragma unroll
  for (int mi = 0; mi < 2; ++mi) {
    const int oc = oc0 + mi * 16 + rb;
    float bv[4] = {0.f, 0.f, 0.f, 0.f};
    if (bias) { bv[0] = bias[oc]; bv[1] = bias[oc + 1]; bv[2] = bias[oc + 2]; bv[3] = bias[oc + 3]; }
#pragma unroll
    for (int ni = 0; ni < 4; ++ni) {
      const int p = ni * 16 + lrow;
      const int gpx = (y0 + (p >> 5)) * 128 + x0 + (p & 31);
      f32x4 a = acc[mi][ni];
      float v[4];
#pragma unroll
      for (int r = 0; r < 4; ++r) v[r] = a[r] + bv[r];
      if (res) {
        int2 rv = *(const int2*)(res + (size_t)gpx * 256 + oc);
        v[0] += f_lo(rv.x); v[1] += f_hi(rv.x); v[2] += f_lo(rv.y); v[3] += f_hi(rv.y);
      }
      if (domod) {
#pragma unroll
        for (int r = 0; r < 4; ++r) v[r] = v[r] * (modAB[oc + r] + 1.f) + modAB[256 + oc + r];
      }
#pragma unroll
      for (int r = 0; r < 4; ++r) v[r] = lrelu(v[r]);
      *(int2*)(out + (size_t)gpx * 256 + oc) = make_int2((int)pk2(v[0], v[1]), (int)pk2(v[2], v[3]));
    }
  }
}

// ---------------- final 256->3 conv, fp32 out ----------------
__global__ __launch_bounds__(256) void kfinal(const short* __restrict__ in,
    const float* __restrict__ w, const float* __restrict__ bias, float* __restrict__ outp) {
  __shared__ float wl[768];
  const int tid = threadIdx.x;
  for (int i = tid; i < 768; i += 256) wl[i] = w[i];
  __syncthreads();
  const int lane = tid & 63;
  const int px = blockIdx.x * 8 + (tid >> 6) * 2 + (lane >> 5);
  const int j = lane & 31;
  bf16x8 v = *(const bf16x8*)(in + (size_t)px * 256 + j * 8);
  float s0 = 0.f, s1 = 0.f, s2 = 0.f;
#pragma unroll
  for (int q = 0; q < 8; ++q) {
    float f = b2f(v[q]);
    s0 += f * wl[j * 8 + q];
    s1 += f * wl[256 + j * 8 + q];
    s2 += f * wl[512 + j * 8 + q];
  }
#pragma unroll
  for (int off = 1; off < 32; off <<= 1) {
    s0 += __shfl_xor(s0, off);
    s1 += __shfl_xor(s1, off);
    s2 += __shfl_xor(s2, off);
  }
  if (j == 0) {
    outp[px] = s0 + bias[0];
    outp[NPIX + px] = s1 + bias[1];
    outp[2 * NPIX + px] = s2 + bias[2];
  }
}

extern "C" void kernel_launch(void* const* d_in, const int* in_sizes, int n_in,
                              void* d_out, int out_size, void* d_ws, size_t ws_size,
                              hipStream_t stream) {
  (void)in_sizes; (void)n_in; (void)out_size; (void)d_ws; (void)ws_size;
  const float* x    = (const float*)d_in[0];
  const float* m    = (const float*)d_in[1];
  const float* z    = (const float*)d_in[2];
  const float* dists= (const float*)d_in[3];
  const float* w1   = (const float*)d_in[4];
  const float* b1   = (const float*)d_in[5];
  const float* wma  = (const float*)d_in[6];
  const float* mlw  = (const float*)d_in[7];
  const float* mlwa = (const float*)d_in[8];
  const float* mlba = (const float*)d_in[9];
  const float* mlwb = (const float*)d_in[10];
  const float* mlbb = (const float*)d_in[11];
  const float* wsig = (const float*)d_in[12];
  const float* bsig = (const float*)d_in[13];
  const float* wc   = (const float*)d_in[14];
  const float* bc   = (const float*)d_in[15];
  const float* wz   = (const float*)d_in[16];
  const float* bz   = (const float*)d_in[17];
  const float* c1w  = (const float*)d_in[18];
  const float* c1b  = (const float*)d_in[19];
  const float* c2aw = (const float*)d_in[20];
  const float* c2ab = (const float*)d_in[21];
  const float* c2bw = (const float*)d_in[22];
  const float* c3aw = (const float*)d_in[23];
  const float* c3ab = (const float*)d_in[24];
  const float* c3bw = (const float*)d_in[25];
  const float* c4aw = (const float*)d_in[26];
  const float* c4ab = (const float*)d_in[27];
  const float* c4bw = (const float*)d_in[28];
  const float* c4bb = (const float*)d_in[29];
  const float* c4w  = (const float*)d_in[30];
  const float* c4b  = (const float*)d_in[31];
  float* outp = (float*)d_out;

  short *pW2, *pFb, *pY1, *pY2, *pY3, *pT;
  float *pAmod;
  hipGetSymbolAddress((void**)&pW2, HIP_SYMBOL(g_wpack2));
  hipGetSymbolAddress((void**)&pFb, HIP_SYMBOL(g_featb));
  hipGetSymbolAddress((void**)&pY1, HIP_SYMBOL(g_y1));
  hipGetSymbolAddress((void**)&pY2, HIP_SYMBOL(g_y2));
  hipGetSymbolAddress((void**)&pY3, HIP_SYMBOL(g_y3));
  hipGetSymbolAddress((void**)&pT,  HIP_SYMBOL(g_t));
  hipGetSymbolAddress((void**)&pAmod, HIP_SYMBOL(g_amod));

  kparams<<<1, 256, 0, stream>>>(z, mlwa, mlba, mlwb, mlbb, wz, bz);
  kprep<<<1504, 256, 0, stream>>>(w1, wma, mlw, wc);
  kprep_cnn<<<9792, 256, 0, stream>>>(c1w, c2aw, c2bw, c3aw, c3bw, c4aw, c4bw);
  kmlp_mfma<<<4096, 256, 0, stream>>>(x, m, b1, bc, wsig, bsig);
  kcomposite<<<4096, 256, 0, stream>>>(dists);
  // RenderCNN (bf16, px-major)
  kgemm1x1<64> <<<512, 256, 0, stream>>>(pFb, pW2 + O_C1,  c1b,  nullptr, 0, nullptr, pY1);  // y1
  kconv3<<<512, 256, 0, stream>>>(pY1, pW2 + O_C2A, c2ab, nullptr, 0, nullptr,      pT);     // t = lrelu(c2a(y1))
  kconv3<<<512, 256, 0, stream>>>(pT,  pW2 + O_C2B, nullptr, pY1, 1, pAmod,         pY2);    // y2m
  kconv3<<<512, 256, 0, stream>>>(pY2, pW2 + O_C3A, c3ab, nullptr, 0, nullptr,      pT);     // t = lrelu(c3a(y2m))
  kconv3<<<512, 256, 0, stream>>>(pT,  pW2 + O_C3B, nullptr, pY2, 1, pAmod + 512,   pY3);    // y3m
  kgemm1x1<256><<<512, 256, 0, stream>>>(pY3, pW2 + O_C4A, c4ab, nullptr, 0, nullptr, pT);   // t = lrelu(c4a(y3m))
  kgemm1x1<256><<<512, 256, 0, stream>>>(pT,  pW2 + O_C4B, c4bb, pY3,    0, nullptr, pY1);   // y4
  kfinal<<<2048, 256, 0, stream>>>(pY1, c4w, c4b, outp);
}